// Round 6
// baseline (827.902 us; speedup 1.0000x reference)
//
#include <hip/hip_runtime.h>
#include <cstdint>
#include <cstddef>

#define D_MODEL 512
#define NHEADS  8
#define EDIM    64
#define BATCH   8
#define LSEQ    4096

typedef unsigned short u16;
typedef __attribute__((ext_vector_type(8))) short short8;
typedef __attribute__((ext_vector_type(4))) float f32x4;

// ===================== fp32 -> 2-term bf16 split ===========================
__device__ __forceinline__ u16 bf16_rne(float x) {
  unsigned int u = __float_as_uint(x);
  u += 0x7FFFu + ((u >> 16) & 1u);
  return (u16)(u >> 16);
}
__device__ __forceinline__ void split2(float x, u16& h, u16& l) {
  h = bf16_rne(x);
  float hf = __uint_as_float((unsigned int)h << 16);
  l = bf16_rne(x - hf);
}

// W (512x512 fp32, k-major) -> transposed planes WT[n][k] (h,l), 4 weights
__global__ __launch_bounds__(256) void cvt_w(
    const float* __restrict__ W0, const float* __restrict__ W1,
    const float* __restrict__ W2, const float* __restrict__ W3,
    u16* __restrict__ out) {
  const float* W = (blockIdx.z == 0) ? W0 : ((blockIdx.z == 1) ? W1 :
                   ((blockIdx.z == 2) ? W2 : W3));
  u16* P = out + (size_t)blockIdx.z * 524288;       // 2 planes of 262144
  __shared__ float tile[64][65];
  const int k0 = blockIdx.x * 64, n0 = blockIdx.y * 64;
  const int t = threadIdx.x;
  const int tr = t >> 4, tc = (t & 15) * 4;
#pragma unroll
  for (int j = 0; j < 4; ++j) {
    int kr = tr + j * 16;
    float4 v = *(const float4*)(W + (size_t)(k0 + kr) * 512 + n0 + tc);
    tile[kr][tc + 0] = v.x; tile[kr][tc + 1] = v.y;
    tile[kr][tc + 2] = v.z; tile[kr][tc + 3] = v.w;
  }
  __syncthreads();
#pragma unroll
  for (int j = 0; j < 4; ++j) {
    int nr = tr + j * 16;
    ushort4 h, l;
    split2(tile[tc + 0][nr], h.x, l.x);
    split2(tile[tc + 1][nr], h.y, l.y);
    split2(tile[tc + 2][nr], h.z, l.z);
    split2(tile[tc + 3][nr], h.w, l.w);
    size_t off = (size_t)(n0 + nr) * 512 + k0 + tc;
    *(ushort4*)(P + off) = h;
    *(ushort4*)(P + 262144 + off) = l;
  }
}

__device__ __forceinline__ void gld_lds16(const char* g, char* l) {
  __builtin_amdgcn_global_load_lds((const __attribute__((address_space(1))) void*)g,
                                   (__attribute__((address_space(3))) void*)l, 16, 0, 0);
}

// ========== fused fp32->split-bf16 + MFMA GEMM, 2-phase pipelined ==========
// 128x128 tile, BK=32, 4 waves, double-buffered LDS (72 KB, 2 blocks/CU).
// Per K-step: {issue A-loads(k+1) to regs || issue B global_load_lds(k+1)
// into buf^1} -> ds_read+48 MFMA on buf -> split+ds_write A(k+1) -> ONE
// barrier (was two full drains + serialized staging). 3-term split:
// acc += Ah*Bh + Ah*Bl + Al*Bh (~2^-18 rel). z selects {Q,K,V} operand.
__global__ __launch_bounds__(256, 2) void gemm_fused(
    const float* __restrict__ X0, const float* __restrict__ X1,
    const float* __restrict__ X2, const u16* __restrict__ WPbase,
    float* __restrict__ Y0, float* __restrict__ Y1, float* __restrict__ Y2) {
  __shared__ u16 Ah[2][128 * 40];
  __shared__ u16 Al[2][128 * 40];
  __shared__ u16 Bh[2][128 * 32];
  __shared__ u16 Bl[2][128 * 32];
  const int z = blockIdx.z;
  const float* X = (z == 0) ? X0 : ((z == 1) ? X1 : X2);
  float* Y = (z == 0) ? Y0 : ((z == 1) ? Y1 : Y2);
  const u16* WP = WPbase + (size_t)z * 524288;

  const int tid = threadIdx.x;
  const int lane = tid & 63, wv = tid >> 6;
  const int wm = (wv & 1) * 64, wn = (wv >> 1) * 64;
  const int bn = blockIdx.x * 128, bm = blockIdx.y * 128;
  const int fr = lane & 15, quad = lane >> 4;
  const int sRow = tid >> 2, sColB = (tid & 3) * 16;
  const int ar = tid >> 1, ac = (tid & 1) * 16;   // A staging: row, col half

  f32x4 acc[16];
#pragma unroll
  for (int i = 0; i < 16; ++i) acc[i] = (f32x4){0.f, 0.f, 0.f, 0.f};

  const u16* Wh = WP;
  const u16* Wl = WP + 262144;
  const float* Arow = X + (size_t)(bm + ar) * 512 + ac;

  union V8 { ushort4 v4[2]; short8 v8; };

  // ---- prologue: stage k=0 into buf 0 ----
  {
    float4 x0 = *(const float4*)(Arow);
    float4 x1 = *(const float4*)(Arow + 4);
    float4 x2 = *(const float4*)(Arow + 8);
    float4 x3 = *(const float4*)(Arow + 12);
#pragma unroll
    for (int j = 0; j < 2; ++j) {
      const size_t rB = (size_t)(bn + j * 64 + sRow) * 512;
      const int lo = (j * 256 + wv * 64) * 16;
      gld_lds16((const char*)(Wh + rB) + sColB, (char*)Bh[0] + lo);
      gld_lds16((const char*)(Wl + rB) + sColB, (char*)Bl[0] + lo);
    }
    V8 h0, l0, h1, l1;
    split2(x0.x, h0.v4[0].x, l0.v4[0].x);
    split2(x0.y, h0.v4[0].y, l0.v4[0].y);
    split2(x0.z, h0.v4[0].z, l0.v4[0].z);
    split2(x0.w, h0.v4[0].w, l0.v4[0].w);
    split2(x1.x, h0.v4[1].x, l0.v4[1].x);
    split2(x1.y, h0.v4[1].y, l0.v4[1].y);
    split2(x1.z, h0.v4[1].z, l0.v4[1].z);
    split2(x1.w, h0.v4[1].w, l0.v4[1].w);
    split2(x2.x, h1.v4[0].x, l1.v4[0].x);
    split2(x2.y, h1.v4[0].y, l1.v4[0].y);
    split2(x2.z, h1.v4[0].z, l1.v4[0].z);
    split2(x2.w, h1.v4[0].w, l1.v4[0].w);
    split2(x3.x, h1.v4[1].x, l1.v4[1].x);
    split2(x3.y, h1.v4[1].y, l1.v4[1].y);
    split2(x3.z, h1.v4[1].z, l1.v4[1].z);
    split2(x3.w, h1.v4[1].w, l1.v4[1].w);
    *(short8*)&Ah[0][ar * 40 + ac]     = h0.v8;
    *(short8*)&Ah[0][ar * 40 + ac + 8] = h1.v8;
    *(short8*)&Al[0][ar * 40 + ac]     = l0.v8;
    *(short8*)&Al[0][ar * 40 + ac + 8] = l1.v8;
  }
  __syncthreads();

  for (int kk = 0; kk < 16; ++kk) {
    const int cur = kk & 1, nxt = cur ^ 1;
    float4 x0, x1, x2, x3;
    if (kk < 15) {
      // issue next A-loads (regs) and B-loads (direct to LDS buf^1) early:
      // their latency hides under this step's 48 MFMAs.
      x0 = *(const float4*)(Arow + (kk + 1) * 32);
      x1 = *(const float4*)(Arow + (kk + 1) * 32 + 4);
      x2 = *(const float4*)(Arow + (kk + 1) * 32 + 8);
      x3 = *(const float4*)(Arow + (kk + 1) * 32 + 12);
#pragma unroll
      for (int j = 0; j < 2; ++j) {
        const size_t rB = (size_t)(bn + j * 64 + sRow) * 512 + (kk + 1) * 32;
        const int lo = (j * 256 + wv * 64) * 16;
        gld_lds16((const char*)(Wh + rB) + sColB, (char*)Bh[nxt] + lo);
        gld_lds16((const char*)(Wl + rB) + sColB, (char*)Bl[nxt] + lo);
      }
    }
    short8 ah[4], al[4], bh4[4], bl4[4];
#pragma unroll
    for (int mi = 0; mi < 4; ++mi) {
      ah[mi] = *(const short8*)&Ah[cur][(wm + mi * 16 + fr) * 40 + quad * 8];
      al[mi] = *(const short8*)&Al[cur][(wm + mi * 16 + fr) * 40 + quad * 8];
    }
#pragma unroll
    for (int ni = 0; ni < 4; ++ni) {
      bh4[ni] = *(const short8*)&Bh[cur][(wn + ni * 16 + fr) * 32 + quad * 8];
      bl4[ni] = *(const short8*)&Bl[cur][(wn + ni * 16 + fr) * 32 + quad * 8];
    }
#pragma unroll
    for (int mi = 0; mi < 4; ++mi)
#pragma unroll
      for (int ni = 0; ni < 4; ++ni)
        acc[mi * 4 + ni] = __builtin_amdgcn_mfma_f32_16x16x32_bf16(
            ah[mi], bh4[ni], acc[mi * 4 + ni], 0, 0, 0);
#pragma unroll
    for (int mi = 0; mi < 4; ++mi)
#pragma unroll
      for (int ni = 0; ni < 4; ++ni)
        acc[mi * 4 + ni] = __builtin_amdgcn_mfma_f32_16x16x32_bf16(
            ah[mi], bl4[ni], acc[mi * 4 + ni], 0, 0, 0);
#pragma unroll
    for (int mi = 0; mi < 4; ++mi)
#pragma unroll
      for (int ni = 0; ni < 4; ++ni)
        acc[mi * 4 + ni] = __builtin_amdgcn_mfma_f32_16x16x32_bf16(
            al[mi], bh4[ni], acc[mi * 4 + ni], 0, 0, 0);
    if (kk < 15) {
      V8 h0, l0, h1, l1;
      split2(x0.x, h0.v4[0].x, l0.v4[0].x);
      split2(x0.y, h0.v4[0].y, l0.v4[0].y);
      split2(x0.z, h0.v4[0].z, l0.v4[0].z);
      split2(x0.w, h0.v4[0].w, l0.v4[0].w);
      split2(x1.x, h0.v4[1].x, l0.v4[1].x);
      split2(x1.y, h0.v4[1].y, l0.v4[1].y);
      split2(x1.z, h0.v4[1].z, l0.v4[1].z);
      split2(x1.w, h0.v4[1].w, l0.v4[1].w);
      split2(x2.x, h1.v4[0].x, l1.v4[0].x);
      split2(x2.y, h1.v4[0].y, l1.v4[0].y);
      split2(x2.z, h1.v4[0].z, l1.v4[0].z);
      split2(x2.w, h1.v4[0].w, l1.v4[0].w);
      split2(x3.x, h1.v4[1].x, l1.v4[1].x);
      split2(x3.y, h1.v4[1].y, l1.v4[1].y);
      split2(x3.z, h1.v4[1].z, l1.v4[1].z);
      split2(x3.w, h1.v4[1].w, l1.v4[1].w);
      *(short8*)&Ah[nxt][ar * 40 + ac]     = h0.v8;
      *(short8*)&Ah[nxt][ar * 40 + ac + 8] = h1.v8;
      *(short8*)&Al[nxt][ar * 40 + ac]     = l0.v8;
      *(short8*)&Al[nxt][ar * 40 + ac + 8] = l1.v8;
    }
    __syncthreads();   // drains B gld_lds (vmcnt) + A ds_writes for buf^1
  }
#pragma unroll
  for (int mi = 0; mi < 4; ++mi)
#pragma unroll
    for (int ni = 0; ni < 4; ++ni) {
      const f32x4 a = acc[mi * 4 + ni];
      float* yp = Y + (size_t)(bm + wm + mi * 16 + quad * 4) * 512 + (bn + wn + ni * 16 + fr);
#pragma unroll
      for (int r = 0; r < 4; ++r) yp[(size_t)r * 512] = a[r];
    }
}

// ================= QK_sample -> M, half-row per pass =======================
// 8-lane dot groups, 2 samples/iter, 2-iteration (4-sample) prefetch.
__global__ __launch_bounds__(256) void qk_sample_half(
    const float* __restrict__ Q, const float* __restrict__ K,
    const int* __restrict__ sidx, float* __restrict__ M, int S, int hg) {
  const int blk = blockIdx.x;
  const int lane = threadIdx.x & 63;
  const int b = blk & 7;                      // XCD swizzle: batch <-> XCD
  const int q = ((blk >> 3) << 2) + (threadIdx.x >> 6);
  const int s = lane >> 5;                    // sample parity
  const int hl = (lane >> 3) & 3;             // head within group
  const int d = lane & 7;                     // dim octet
  const int h = hg * 4 + hl;
  const int col = hg * 256 + hl * 64 + d * 8;

  const float* Qp = Q + ((size_t)b * LSEQ + q) * D_MODEL + col;
  const float4 q0 = *(const float4*)Qp;
  const float4 q1 = *(const float4*)(Qp + 4);
  const float* Kb = K + (size_t)b * LSEQ * D_MODEL + col;
  const int* sp = sidx + (size_t)q * S;

  auto rowp = [&](int j) -> const float* {
    int jj = j + s;
    int row = sp[(jj < S) ? jj : (S - 1)];
    return Kb + (size_t)row * D_MODEL;
  };

  const float* pr0 = rowp(0);
  float4 a0 = *(const float4*)pr0, b0 = *(const float4*)(pr0 + 4);
  const float* pr1 = rowp(2);
  float4 a1 = *(const float4*)pr1, b1 = *(const float4*)(pr1 + 4);

  float mx = -3.4e38f, sum = 0.0f;
  for (int j = 0; j < S; j += 2) {
    const float4 ca = a0, cb = b0;
    a0 = a1; b0 = b1;
    const float* pn = rowp(j + 4);
    a1 = *(const float4*)pn;
    b1 = *(const float4*)(pn + 4);
    float p = ca.x * q0.x + ca.y * q0.y + ca.z * q0.z + ca.w * q0.w +
              cb.x * q1.x + cb.y * q1.y + cb.z * q1.z + cb.w * q1.w;
    p += __shfl_xor(p, 1, 64);
    p += __shfl_xor(p, 2, 64);
    p += __shfl_xor(p, 4, 64);   // 8-lane group done
    if (j + s < S) {
      mx = fmaxf(mx, p);
      sum += p;
    }
  }
  mx = fmaxf(mx, __shfl_xor(mx, 32, 64));
  sum += __shfl_xor(sum, 32, 64);
  if (s == 0 && d == 0)
    M[((size_t)(b * NHEADS + h)) * LSEQ + q] = mx - sum / (float)S;
}

// ===================== top-U indices per (b,h) =============================
// wave-shuffle argmax (6 stages) + 2 barriers/iter (was 9-barrier LDS tree).
__global__ __launch_bounds__(256) void topk_kernel(
    const float* __restrict__ M, int* __restrict__ Mtop, int U) {
  __shared__ float vals[LSEQ];
  __shared__ float wbest[4];
  __shared__ int widx[4];
  int bh = blockIdx.x;
  int t = threadIdx.x;
  const int w = t >> 6, lane = t & 63;
  for (int i = t; i < LSEQ; i += 256) vals[i] = M[(size_t)bh * LSEQ + i];
  __syncthreads();
  for (int it = 0; it < U; ++it) {
    float best = -3.4e38f; int bi = 0x7fffffff;
    for (int i = t; i < LSEQ; i += 256) {
      float v = vals[i];
      if (v > best) { best = v; bi = i; }
    }
#pragma unroll
    for (int o = 1; o < 64; o <<= 1) {
      float ov = __shfl_xor(best, o, 64);
      int oi = __shfl_xor(bi, o, 64);
      if (ov > best || (ov == best && oi < bi)) { best = ov; bi = oi; }
    }
    if (lane == 0) { wbest[w] = best; widx[w] = bi; }
    __syncthreads();
    if (t == 0) {
      float B = wbest[0]; int I = widx[0];
#pragma unroll
      for (int w2 = 1; w2 < 4; ++w2)
        if (wbest[w2] > B || (wbest[w2] == B && widx[w2] < I)) {
          B = wbest[w2]; I = widx[w2];
        }
      Mtop[(size_t)bh * U + it] = I;
      vals[I] = -3.4e38f;
    }
    __syncthreads();
  }
}

// ============== flash attention over top-U rows, key-split =================
// MFMA QK^T (swapped: S^T = mfma(K, Q)) + fp32 VALU PV.
__global__ __launch_bounds__(256, 2) void attn_flash(
    const float* __restrict__ Q, const float* __restrict__ K,
    const float* __restrict__ V, const int* __restrict__ Mtop,
    float* __restrict__ part_ctx, float* __restrict__ part_m,
    float* __restrict__ part_l, int U, int nsplit, int chunks_per_block) {
  __shared__ u16 KhS[64 * 72];
  __shared__ u16 KlS[64 * 72];
  __shared__ float VsS[64 * 68];
  const int bh = blockIdx.y, split = blockIdx.x;
  const int h = bh & (NHEADS - 1), b = bh >> 3;
  const int t = threadIdx.x, w = t >> 6, lane = t & 63;
  const int fr = lane & 15, quad = lane >> 4;

  const int qi = w * 16 + fr;
  const int qrow = (qi < U) ? Mtop[(size_t)bh * U + qi] : Mtop[(size_t)bh * U];
  const float4* Qr = (const float4*)(Q + ((size_t)(b * LSEQ) + qrow) * D_MODEL + h * EDIM);
  float4 qa = Qr[quad * 2], qb = Qr[quad * 2 + 1];
  float4 qc = Qr[quad * 2 + 8], qd = Qr[quad * 2 + 9];
  short8 qh0, ql0, qh1, ql1;
  {
    u16 hh, ll;
    split2(qa.x, hh, ll); qh0[0] = (short)hh; ql0[0] = (short)ll;
    split2(qa.y, hh, ll); qh0[1] = (short)hh; ql0[1] = (short)ll;
    split2(qa.z, hh, ll); qh0[2] = (short)hh; ql0[2] = (short)ll;
    split2(qa.w, hh, ll); qh0[3] = (short)hh; ql0[3] = (short)ll;
    split2(qb.x, hh, ll); qh0[4] = (short)hh; ql0[4] = (short)ll;
    split2(qb.y, hh, ll); qh0[5] = (short)hh; ql0[5] = (short)ll;
    split2(qb.z, hh, ll); qh0[6] = (short)hh; ql0[6] = (short)ll;
    split2(qb.w, hh, ll); qh0[7] = (short)hh; ql0[7] = (short)ll;
    split2(qc.x, hh, ll); qh1[0] = (short)hh; ql1[0] = (short)ll;
    split2(qc.y, hh, ll); qh1[1] = (short)hh; ql1[1] = (short)ll;
    split2(qc.z, hh, ll); qh1[2] = (short)hh; ql1[2] = (short)ll;
    split2(qc.w, hh, ll); qh1[3] = (short)hh; ql1[3] = (short)ll;
    split2(qd.x, hh, ll); qh1[4] = (short)hh; ql1[4] = (short)ll;
    split2(qd.y, hh, ll); qh1[5] = (short)hh; ql1[5] = (short)ll;
    split2(qd.z, hh, ll); qh1[6] = (short)hh; ql1[6] = (short)ll;
    split2(qd.w, hh, ll); qh1[7] = (short)hh; ql1[7] = (short)ll;
  }

  float4 c4[16];
#pragma unroll
  for (int i = 0; i < 16; ++i) c4[i] = make_float4(0.f, 0.f, 0.f, 0.f);
  float m = -1e30f, l = 0.0f;

  const int r = t >> 2, cg = t & 3;

  const int k_base = split * (chunks_per_block * 64);
  for (int c = 0; c < chunks_per_block; ++c) {
    const int k0 = k_base + c * 64;
    const float4* Kg4 = (const float4*)(K + ((size_t)(b * LSEQ) + k0 + r) * D_MODEL + h * EDIM);
    const float4* Vg4 = (const float4*)(V + ((size_t)(b * LSEQ) + k0 + r) * D_MODEL + h * EDIM);
#pragma unroll
    for (int i = 0; i < 4; ++i) {
      const int f4 = cg + 4 * i;
      float4 kv = Kg4[f4];
      float4 vv = Vg4[f4];
      ushort4 hh, ll;
      split2(kv.x, hh.x, ll.x);
      split2(kv.y, hh.y, ll.y);
      split2(kv.z, hh.z, ll.z);
      split2(kv.w, hh.w, ll.w);
      *(ushort4*)&KhS[r * 72 + f4 * 4] = hh;
      *(ushort4*)&KlS[r * 72 + f4 * 4] = ll;
      *(float4*)&VsS[r * 68 + f4 * 4] = vv;
    }
    __syncthreads();

    f32x4 acc[4];
#pragma unroll
    for (int mt = 0; mt < 4; ++mt) acc[mt] = (f32x4){0.f, 0.f, 0.f, 0.f};
#pragma unroll
    for (int mt = 0; mt < 4; ++mt) {
      short8 kh = *(const short8*)&KhS[(mt * 16 + fr) * 72 + quad * 8];
      short8 kl = *(const short8*)&KlS[(mt * 16 + fr) * 72 + quad * 8];
      acc[mt] = __builtin_amdgcn_mfma_f32_16x16x32_bf16(kh, qh0, acc[mt], 0, 0, 0);
      acc[mt] = __builtin_amdgcn_mfma_f32_16x16x32_bf16(kh, ql0, acc[mt], 0, 0, 0);
      acc[mt] = __builtin_amdgcn_mfma_f32_16x16x32_bf16(kl, qh0, acc[mt], 0, 0, 0);
    }
#pragma unroll
    for (int mt = 0; mt < 4; ++mt) {
      short8 kh = *(const short8*)&KhS[(mt * 16 + fr) * 72 + 32 + quad * 8];
      short8 kl = *(const short8*)&KlS[(mt * 16 + fr) * 72 + 32 + quad * 8];
      acc[mt] = __builtin_amdgcn_mfma_f32_16x16x32_bf16(kh, qh1, acc[mt], 0, 0, 0);
      acc[mt] = __builtin_amdgcn_mfma_f32_16x16x32_bf16(kh, ql1, acc[mt], 0, 0, 0);
      acc[mt] = __builtin_amdgcn_mfma_f32_16x16x32_bf16(kl, qh1, acc[mt], 0, 0, 0);
    }

    float cm = -3.4e38f;
#pragma unroll
    for (int mt = 0; mt < 4; ++mt) {
#pragma unroll
      for (int rr = 0; rr < 4; ++rr) {
        float s = acc[mt][rr] * 0.125f;
        acc[mt][rr] = s;
        cm = fmaxf(cm, s);
      }
    }
    cm = fmaxf(cm, __shfl_xor(cm, 16, 64));
    cm = fmaxf(cm, __shfl_xor(cm, 32, 64));
    float mn = fmaxf(m, cm);
    if (mn > m) {
      float f = __expf(m - mn);
      l *= f;
#pragma unroll
      for (int i = 0; i < 16; ++i) {
        c4[i].x *= f; c4[i].y *= f; c4[i].z *= f; c4[i].w *= f;
      }
      m = mn;
    }
    float psum = 0.0f;
#pragma unroll
    for (int mt = 0; mt < 4; ++mt) {
#pragma unroll
      for (int rr = 0; rr < 4; ++rr) {
        float p = __expf(acc[mt][rr] - m);
        acc[mt][rr] = p;
        psum += p;
      }
    }
    l += psum;

#pragma unroll
    for (int mt = 0; mt < 4; ++mt) {
#pragma unroll
      for (int rr = 0; rr < 4; ++rr) {
        const int krow = mt * 16 + quad * 4 + rr;
        const float4* vr = (const float4*)&VsS[krow * 68];
        const float p = acc[mt][rr];
#pragma unroll
        for (int i = 0; i < 16; ++i) {
          float4 vv = vr[i];
          c4[i].x += p * vv.x; c4[i].y += p * vv.y;
          c4[i].z += p * vv.z; c4[i].w += p * vv.w;
        }
      }
    }
    __syncthreads();
  }

#pragma unroll
  for (int i = 0; i < 16; ++i) {
    c4[i].x += __shfl_xor(c4[i].x, 16, 64);
    c4[i].y += __shfl_xor(c4[i].y, 16, 64);
    c4[i].z += __shfl_xor(c4[i].z, 16, 64);
    c4[i].w += __shfl_xor(c4[i].w, 16, 64);
    c4[i].x += __shfl_xor(c4[i].x, 32, 64);
    c4[i].y += __shfl_xor(c4[i].y, 32, 64);
    c4[i].z += __shfl_xor(c4[i].z, 32, 64);
    c4[i].w += __shfl_xor(c4[i].w, 32, 64);
  }
  l += __shfl_xor(l, 16, 64);
  l += __shfl_xor(l, 32, 64);

  if (quad == 0 && qi < U) {
    part_m[(size_t)(bh * nsplit + split) * 64 + qi] = m;
    part_l[(size_t)(bh * nsplit + split) * 64 + qi] = l;
  }
  float* pc = part_ctx + (size_t)(bh * nsplit + split) * 4096;
  if (quad == 0) {
#pragma unroll
    for (int ii = 0; ii < 16; ++ii) pc[ii * 64 + qi] = (&c4[ii >> 2].x)[ii & 3];
  } else if (quad == 1) {
#pragma unroll
    for (int ii = 0; ii < 16; ++ii) pc[(16 + ii) * 64 + qi] = (&c4[4 + (ii >> 2)].x)[ii & 3];
  } else if (quad == 2) {
#pragma unroll
    for (int ii = 0; ii < 16; ++ii) pc[(32 + ii) * 64 + qi] = (&c4[8 + (ii >> 2)].x)[ii & 3];
  } else {
#pragma unroll
    for (int ii = 0; ii < 16; ++ii) pc[(48 + ii) * 64 + qi] = (&c4[12 + (ii >> 2)].x)[ii & 3];
  }
}

// =================== combine key-split flash partials ======================
__global__ __launch_bounds__(256) void attn_combine(
    const float* __restrict__ part_ctx, const float* __restrict__ part_m,
    const float* __restrict__ part_l, float* __restrict__ ctxTop,
    int U, int nsplit) {
  __shared__ float F[16][64];
  const int bh = blockIdx.x;
  const int t = threadIdx.x, lane = t & 63, grp = t >> 6;
  if (grp == 0) {
    float M = -3.4e38f;
    for (int s = 0; s < nsplit; ++s)
      M = fmaxf(M, part_m[(size_t)(bh * nsplit + s) * 64 + lane]);
    float L = 0.0f;
    for (int s = 0; s < nsplit; ++s)
      L += part_l[(size_t)(bh * nsplit + s) * 64 + lane] *
           __expf(part_m[(size_t)(bh * nsplit + s) * 64 + lane] - M);
    float invL = 1.0f / L;
    for (int s = 0; s < nsplit; ++s)
      F[s][lane] = __expf(part_m[(size_t)(bh * nsplit + s) * 64 + lane] - M) * invL;
  }
  __syncthreads();
  for (int ei = 0; ei < 16; ++ei) {
    int e = grp * 16 + ei;
    float acc = 0.0f;
    for (int s = 0; s < nsplit; ++s)
      acc += F[s][lane] * part_ctx[(size_t)(bh * nsplit + s) * 4096 + e * 64 + lane];
    if (lane < U) ctxTop[((size_t)bh * U + lane) * 64 + e] = acc;
  }
}

// ====================== V.mean over keys per (b,h), split 8x ===============
__global__ __launch_bounds__(256) void vmean_part(
    const float* __restrict__ V, float* __restrict__ Vm) {
  __shared__ float part[4][EDIM];
  const int bh = blockIdx.x, chunk = blockIdx.y;
  const int h = bh & (NHEADS - 1), b = bh >> 3;
  const int t = threadIdx.x;
  const int e = t & 63, c = t >> 6;
  float s = 0.0f;
  const int k0 = chunk * 512 + c * 128;
  for (int k = k0; k < k0 + 128; ++k)
    s += V[((size_t)b * LSEQ + k) * D_MODEL + h * EDIM + e];
  part[c][e] = s;
  __syncthreads();
  if (c == 0)
    atomicAdd(&Vm[(size_t)bh * EDIM + e],
              (part[0][e] + part[1][e] + part[2][e] + part[3][e]) *
                  (1.0f / (float)LSEQ));
}

// ============ base_out[b] = concat_h(Vmean[b,h]) @ W_out + b_out ===========
__global__ __launch_bounds__(256) void base_out_kernel(
    const float* __restrict__ Vm, const float* __restrict__ Wout,
    const float* __restrict__ bout, float* __restrict__ base) {
  __shared__ float cb[D_MODEL];
  int b = blockIdx.x;
  int t = threadIdx.x;
  for (int d = t; d < D_MODEL; d += 256) cb[d] = Vm[(size_t)b * D_MODEL + d];
  __syncthreads();
  for (int n = t; n < D_MODEL; n += 256) {
    float s = bout[n];
    for (int d = 0; d < D_MODEL; ++d) s += cb[d] * Wout[(size_t)d * D_MODEL + n];
    base[(size_t)b * D_MODEL + n] = s;
  }
}

// ================== broadcast base row into all output rows ================
__global__ __launch_bounds__(256) void fill_out(
    const float* __restrict__ base, float* __restrict__ out) {
  size_t i = (size_t)blockIdx.x * 256 + threadIdx.x;
  int n4 = (int)(i & 127);
  size_t bq = i >> 7;
  int b = (int)(bq >> 12);
  float4 v = ((const float4*)base)[(size_t)b * 128 + n4];
  ((float4*)out)[i] = v;
}

// ====== add (ctxTop - Vmean) @ W_out[h-slice] into the top rows (MFMA) =====
__global__ __launch_bounds__(256, 1) void delta_out_mfma(
    const float* __restrict__ ctxTop, const float* __restrict__ Vm,
    const int* __restrict__ Mtop, const u16* __restrict__ WoutTP,
    float* __restrict__ out, int U) {
  __shared__ u16 Dh[64 * 72];
  __shared__ u16 Dl[64 * 72];
  __shared__ int qr[64];
  const int bh = blockIdx.x;
  const int h = bh & (NHEADS - 1), b = bh >> 3;
  const int t = threadIdx.x, lane = t & 63, wv = t >> 6;
  const int fr = lane & 15, quad = lane >> 4;

  {
    const int r = t >> 2, c0 = (t & 3) * 16;
#pragma unroll
    for (int j = 0; j < 4; ++j) {
      float4 v = make_float4(0.f, 0.f, 0.f, 0.f);
      if (r < U) {
        float4 cv = *(const float4*)(ctxTop + ((size_t)bh * U + r) * EDIM + c0 + j * 4);
        float4 mv = *(const float4*)(Vm + (size_t)bh * EDIM + c0 + j * 4);
        v = make_float4(cv.x - mv.x, cv.y - mv.y, cv.z - mv.z, cv.w - mv.w);
      }
      ushort4 hh, ll;
      split2(v.x, hh.x, ll.x);
      split2(v.y, hh.y, ll.y);
      split2(v.z, hh.z, ll.z);
      split2(v.w, hh.w, ll.w);
      *(ushort4*)&Dh[r * 72 + c0 + j * 4] = hh;
      *(ushort4*)&Dl[r * 72 + c0 + j * 4] = ll;
    }
  }
  if (t < 64) qr[t] = (t < U) ? Mtop[(size_t)bh * U + t] : -1;
  __syncthreads();

  f32x4 acc[32];   // [mt(4)][nt(8)]
#pragma unroll
  for (int i = 0; i < 32; ++i) acc[i] = (f32x4){0.f, 0.f, 0.f, 0.f};

  const u16* Wh = WoutTP;
  const u16* Wl = WoutTP + 262144;

#pragma unroll
  for (int ks = 0; ks < 2; ++ks) {
    short8 a_h[4], a_l[4];
#pragma unroll
    for (int mt = 0; mt < 4; ++mt) {
      a_h[mt] = *(const short8*)&Dh[(mt * 16 + fr) * 72 + ks * 32 + quad * 8];
      a_l[mt] = *(const short8*)&Dl[(mt * 16 + fr) * 72 + ks * 32 + quad * 8];
    }
#pragma unroll
    for (int nt = 0; nt < 8; ++nt) {
      const int n = wv * 128 + nt * 16 + fr;
      const size_t off = (size_t)n * 512 + h * EDIM + ks * 32 + quad * 8;
      short8 b_h = *(const short8*)&Wh[off];
      short8 b_l = *(const short8*)&Wl[off];
#pragma unroll
      for (int mt = 0; mt < 4; ++mt) {
        acc[mt * 8 + nt] = __builtin_amdgcn_mfma_f32_16x16x32_bf16(
            a_h[mt], b_h, acc[mt * 8 + nt], 0, 0, 0);
        acc[mt * 8 + nt] = __builtin_amdgcn_mfma_f32_16x16x32_bf16(
            a_h[mt], b_l, acc[mt * 8 + nt], 0, 0, 0);
        acc[mt * 8 + nt] = __builtin_amdgcn_mfma_f32_16x16x32_bf16(
            a_l[mt], b_h, acc[mt * 8 + nt], 0, 0, 0);
      }
    }
  }

  int qreg[16];
#pragma unroll
  for (int mt = 0; mt < 4; ++mt)
#pragma unroll
    for (int r4 = 0; r4 < 4; ++r4) qreg[mt * 4 + r4] = qr[mt * 16 + quad * 4 + r4];
#pragma unroll
  for (int mt = 0; mt < 4; ++mt)
#pragma unroll
    for (int nt = 0; nt < 8; ++nt) {
      const f32x4 a = acc[mt * 8 + nt];
      const int n = wv * 128 + nt * 16 + fr;
#pragma unroll
      for (int r4 = 0; r4 < 4; ++r4) {
        const int q = qreg[mt * 4 + r4];
        if (q >= 0)
          atomicAdd(out + ((size_t)b * LSEQ + q) * D_MODEL + n, a[r4]);
      }
    }
}

// ===========================================================================
extern "C" void kernel_launch(void* const* d_in, const int* in_sizes, int n_in,
                              void* d_out, int out_size, void* d_ws, size_t ws_size,
                              hipStream_t stream) {
  const float* query  = (const float*)d_in[0];
  const float* key_in = (const float*)d_in[1];
  const float* value  = (const float*)d_in[2];
  const float* W_Q    = (const float*)d_in[3];
  const float* W_K    = (const float*)d_in[4];
  const float* W_V    = (const float*)d_in[5];
  const float* W_out  = (const float*)d_in[6];
  const float* b_out  = (const float*)d_in[7];
  const int*   sidx   = (const int*)d_in[8];
  float* out = (float*)d_out;

  const int S = in_sizes[8] / LSEQ;   // 41
  const int U = S;

  char* ws = (char*)d_ws;
  size_t o = 0;
  float* Qf     = (float*)(ws + o); o += (size_t)BATCH * LSEQ * D_MODEL * 4;
  float* Kf     = (float*)(ws + o); o += (size_t)BATCH * LSEQ * D_MODEL * 4;
  float* Vf     = (float*)(ws + o); o += (size_t)BATCH * LSEQ * D_MODEL * 4;
  int*   Mtop   = (int*)  (ws + o); o += ((size_t)64 * U * 4 + 255) & ~255ULL;
  float* ctxTop = (float*)(ws + o); o += ((size_t)64 * U * EDIM * 4 + 255) & ~255ULL;
  float* Vm     = (float*)(ws + o); o += 16384;
  float* baseO  = (float*)(ws + o); o += 16384;
  u16*   Wpl    = (u16*)  (ws + o); o += (size_t)4 * 524288 * 2;   // 4 MB
  size_t unionOff = o;   // M / flash partials (disjoint lifetimes)

  float* M = (float*)(ws + unionOff);            // 1 MB
  int nsplit = 16;
  for (;;) {
    size_t need = unionOff + 2 * ((size_t)64 * nsplit * 64 * 4)
                  + (size_t)64 * nsplit * 4096 * 4;
    if (need <= ws_size || nsplit == 1) break;
    nsplit >>= 1;
  }
  float* part_m   = (float*)(ws + unionOff);
  float* part_l   = part_m + (size_t)64 * nsplit * 64;
  float* part_ctx = part_l + (size_t)64 * nsplit * 64;
  const int chunks_per_block = 64 / nsplit;

  // ---- projections via pipelined fused split-bf16 MFMA GEMM ----
  cvt_w<<<dim3(8, 8, 4), 256, 0, stream>>>(W_Q, W_K, W_V, W_out, Wpl);
  gemm_fused<<<dim3(4, 256, 3), 256, 0, stream>>>(
      query, key_in, value, Wpl, Qf, Kf, Vf);

  qk_sample_half<<<(BATCH * LSEQ) / 4, 256, 0, stream>>>(Qf, Kf, sidx, M, S, 0);
  qk_sample_half<<<(BATCH * LSEQ) / 4, 256, 0, stream>>>(Qf, Kf, sidx, M, S, 1);
  topk_kernel<<<BATCH * NHEADS, 256, 0, stream>>>(M, Mtop, U);
  attn_flash<<<dim3(nsplit, BATCH * NHEADS), 256, 0, stream>>>(
      Qf, Kf, Vf, Mtop, part_ctx, part_m, part_l, U, nsplit, chunks_per_block);
  attn_combine<<<BATCH * NHEADS, 256, 0, stream>>>(
      part_ctx, part_m, part_l, ctxTop, U, nsplit);
  hipMemsetAsync(Vm, 0, (size_t)BATCH * NHEADS * EDIM * 4, stream);
  vmean_part<<<dim3(BATCH * NHEADS, 8), 256, 0, stream>>>(Vf, Vm);
  base_out_kernel<<<BATCH, 256, 0, stream>>>(Vm, W_out, b_out, baseO);
  fill_out<<<(BATCH * LSEQ * (D_MODEL / 4)) / 256, 256, 0, stream>>>(baseO, out);
  delta_out_mfma<<<BATCH * NHEADS, 256, 0, stream>>>(
      ctxTop, Vm, Mtop, Wpl + (size_t)3 * 524288, out, U);
}

// Round 7
// 738.515 us; speedup vs baseline: 1.1210x; 1.1210x over previous
//
#include <hip/hip_runtime.h>
#include <cstdint>
#include <cstddef>

#define D_MODEL 512
#define NHEADS  8
#define EDIM    64
#define BATCH   8
#define LSEQ    4096

typedef unsigned short u16;
typedef __attribute__((ext_vector_type(8))) short short8;
typedef __attribute__((ext_vector_type(4))) float f32x4;

// ===================== fp32 -> 2-term bf16 split ===========================
__device__ __forceinline__ u16 bf16_rne(float x) {
  unsigned int u = __float_as_uint(x);
  u += 0x7FFFu + ((u >> 16) & 1u);
  return (u16)(u >> 16);
}
__device__ __forceinline__ void split2(float x, u16& h, u16& l) {
  h = bf16_rne(x);
  float hf = __uint_as_float((unsigned int)h << 16);
  l = bf16_rne(x - hf);
}

// W (512x512 fp32, k-major) -> transposed planes WT[n][k] (h,l), 4 weights.
// Within each 64-B k-chunk the 16-B groups are stored PRE-SWIZZLED:
// g' = g ^ (n&3). Consumers stage linearly (global_load_lds) and read with
// the same XOR (which folds to a per-lane constant) -> B-tile ds_read_b128
// drops from 8-way to ~4-way bank conflict at zero instruction cost.
__global__ __launch_bounds__(256) void cvt_w(
    const float* __restrict__ W0, const float* __restrict__ W1,
    const float* __restrict__ W2, const float* __restrict__ W3,
    u16* __restrict__ out) {
  const float* W = (blockIdx.z == 0) ? W0 : ((blockIdx.z == 1) ? W1 :
                   ((blockIdx.z == 2) ? W2 : W3));
  u16* P = out + (size_t)blockIdx.z * 524288;       // 2 planes of 262144
  __shared__ float tile[64][65];
  const int k0 = blockIdx.x * 64, n0 = blockIdx.y * 64;
  const int t = threadIdx.x;
  const int tr = t >> 4, tc = (t & 15) * 4;
#pragma unroll
  for (int j = 0; j < 4; ++j) {
    int kr = tr + j * 16;
    float4 v = *(const float4*)(W + (size_t)(k0 + kr) * 512 + n0 + tc);
    tile[kr][tc + 0] = v.x; tile[kr][tc + 1] = v.y;
    tile[kr][tc + 2] = v.z; tile[kr][tc + 3] = v.w;
  }
  __syncthreads();
#pragma unroll
  for (int j = 0; j < 4; ++j) {
    int nr = tr + j * 16;
    ushort4 h, l;
    split2(tile[tc + 0][nr], h.x, l.x);
    split2(tile[tc + 1][nr], h.y, l.y);
    split2(tile[tc + 2][nr], h.z, l.z);
    split2(tile[tc + 3][nr], h.w, l.w);
    // swizzle: keep bit5 (32-chunk) and bit2 (half-group), XOR group bits
    const int tcs = (tc & 36) | (((((tc >> 3) & 3)) ^ (nr & 3)) << 3);
    size_t off = (size_t)(n0 + nr) * 512 + k0 + tcs;
    *(ushort4*)(P + off) = h;
    *(ushort4*)(P + 262144 + off) = l;
  }
}

__device__ __forceinline__ void gld_lds16(const char* g, char* l) {
  __builtin_amdgcn_global_load_lds((const __attribute__((address_space(1))) void*)g,
                                   (__attribute__((address_space(3))) void*)l, 16, 0, 0);
}

// ========== fused fp32->split-bf16 + MFMA GEMM: Y = X @ W ==================
// 128x128 tile, BK=32, 4 waves, SINGLE-buffered LDS (36 KB -> 4 blocks/CU,
// 16 waves: R6's double-buffer dropped occupancy to 2 blocks/CU and lost).
// A staged from fp32 X with in-register h/l split into padded [128][40]
// rows (2-way, free). B via global_load_lds from the pre-swizzled planes;
// reads apply the matching XOR (per-lane constant). 3-term split:
// acc += Ah*Bh + Ah*Bl + Al*Bh (~2^-18 rel). z selects {Q,K,V}.
__global__ __launch_bounds__(256, 2) void gemm_fused(
    const float* __restrict__ X0, const float* __restrict__ X1,
    const float* __restrict__ X2, const u16* __restrict__ WPbase,
    float* __restrict__ Y0, float* __restrict__ Y1, float* __restrict__ Y2) {
  __shared__ u16 Ah[128 * 40];
  __shared__ u16 Al[128 * 40];
  __shared__ u16 Bh[128 * 32];
  __shared__ u16 Bl[128 * 32];
  const int z = blockIdx.z;
  const float* X = (z == 0) ? X0 : ((z == 1) ? X1 : X2);
  float* Y = (z == 0) ? Y0 : ((z == 1) ? Y1 : Y2);
  const u16* WP = WPbase + (size_t)z * 524288;

  const int tid = threadIdx.x;
  const int lane = tid & 63, wv = tid >> 6;
  const int wm = (wv & 1) * 64, wn = (wv >> 1) * 64;
  const int bn = blockIdx.x * 128, bm = blockIdx.y * 128;
  const int fr = lane & 15, quad = lane >> 4;
  const int bq = (quad ^ (fr & 3)) * 8;          // swizzled B group offset
  const int sRow = tid >> 2, sColB = (tid & 3) * 16;
  const int ar = tid >> 1, ac = (tid & 1) * 16;  // A staging: row, col half

  f32x4 acc[16];
#pragma unroll
  for (int i = 0; i < 16; ++i) acc[i] = (f32x4){0.f, 0.f, 0.f, 0.f};

  const u16* Wh = WP;
  const u16* Wl = WP + 262144;
  const float* Arow = X + (size_t)(bm + ar) * 512 + ac;

  union V8 { ushort4 v4[2]; short8 v8; };

  for (int kk = 0; kk < 16; ++kk) {
    // ---- A: fp32 load -> split -> LDS (padded rows) ----
    float4 x0 = *(const float4*)(Arow + kk * 32);
    float4 x1 = *(const float4*)(Arow + kk * 32 + 4);
    float4 x2 = *(const float4*)(Arow + kk * 32 + 8);
    float4 x3 = *(const float4*)(Arow + kk * 32 + 12);
    // ---- B: global_load_lds from pre-swizzled planes ----
#pragma unroll
    for (int j = 0; j < 2; ++j) {
      const size_t rB = (size_t)(bn + j * 64 + sRow) * 512 + kk * 32;
      const int lo = (j * 256 + wv * 64) * 16;
      gld_lds16((const char*)(Wh + rB) + sColB, (char*)Bh + lo);
      gld_lds16((const char*)(Wl + rB) + sColB, (char*)Bl + lo);
    }
    V8 h0, l0, h1, l1;
    split2(x0.x, h0.v4[0].x, l0.v4[0].x);
    split2(x0.y, h0.v4[0].y, l0.v4[0].y);
    split2(x0.z, h0.v4[0].z, l0.v4[0].z);
    split2(x0.w, h0.v4[0].w, l0.v4[0].w);
    split2(x1.x, h0.v4[1].x, l0.v4[1].x);
    split2(x1.y, h0.v4[1].y, l0.v4[1].y);
    split2(x1.z, h0.v4[1].z, l0.v4[1].z);
    split2(x1.w, h0.v4[1].w, l0.v4[1].w);
    split2(x2.x, h1.v4[0].x, l1.v4[0].x);
    split2(x2.y, h1.v4[0].y, l1.v4[0].y);
    split2(x2.z, h1.v4[0].z, l1.v4[0].z);
    split2(x2.w, h1.v4[0].w, l1.v4[0].w);
    split2(x3.x, h1.v4[1].x, l1.v4[1].x);
    split2(x3.y, h1.v4[1].y, l1.v4[1].y);
    split2(x3.z, h1.v4[1].z, l1.v4[1].z);
    split2(x3.w, h1.v4[1].w, l1.v4[1].w);
    *(short8*)&Ah[ar * 40 + ac]     = h0.v8;
    *(short8*)&Ah[ar * 40 + ac + 8] = h1.v8;
    *(short8*)&Al[ar * 40 + ac]     = l0.v8;
    *(short8*)&Al[ar * 40 + ac + 8] = l1.v8;
    __syncthreads();
    short8 ah[4], al[4], bh4[4], bl4[4];
#pragma unroll
    for (int mi = 0; mi < 4; ++mi) {
      ah[mi] = *(const short8*)&Ah[(wm + mi * 16 + fr) * 40 + quad * 8];
      al[mi] = *(const short8*)&Al[(wm + mi * 16 + fr) * 40 + quad * 8];
    }
#pragma unroll
    for (int ni = 0; ni < 4; ++ni) {
      bh4[ni] = *(const short8*)&Bh[(wn + ni * 16 + fr) * 32 + bq];
      bl4[ni] = *(const short8*)&Bl[(wn + ni * 16 + fr) * 32 + bq];
    }
#pragma unroll
    for (int mi = 0; mi < 4; ++mi)
#pragma unroll
      for (int ni = 0; ni < 4; ++ni)
        acc[mi * 4 + ni] = __builtin_amdgcn_mfma_f32_16x16x32_bf16(
            ah[mi], bh4[ni], acc[mi * 4 + ni], 0, 0, 0);
#pragma unroll
    for (int mi = 0; mi < 4; ++mi)
#pragma unroll
      for (int ni = 0; ni < 4; ++ni)
        acc[mi * 4 + ni] = __builtin_amdgcn_mfma_f32_16x16x32_bf16(
            ah[mi], bl4[ni], acc[mi * 4 + ni], 0, 0, 0);
#pragma unroll
    for (int mi = 0; mi < 4; ++mi)
#pragma unroll
      for (int ni = 0; ni < 4; ++ni)
        acc[mi * 4 + ni] = __builtin_amdgcn_mfma_f32_16x16x32_bf16(
            al[mi], bh4[ni], acc[mi * 4 + ni], 0, 0, 0);
    __syncthreads();
  }
#pragma unroll
  for (int mi = 0; mi < 4; ++mi)
#pragma unroll
    for (int ni = 0; ni < 4; ++ni) {
      const f32x4 a = acc[mi * 4 + ni];
      float* yp = Y + (size_t)(bm + wm + mi * 16 + quad * 4) * 512 + (bn + wn + ni * 16 + fr);
#pragma unroll
      for (int r = 0; r < 4; ++r) yp[(size_t)r * 512] = a[r];
    }
}

// ================= QK_sample -> M, half-row per pass =======================
// 8-lane dot groups, 2 samples/iter, 2-iteration (4-sample) prefetch.
__global__ __launch_bounds__(256) void qk_sample_half(
    const float* __restrict__ Q, const float* __restrict__ K,
    const int* __restrict__ sidx, float* __restrict__ M, int S, int hg) {
  const int blk = blockIdx.x;
  const int lane = threadIdx.x & 63;
  const int b = blk & 7;                      // XCD swizzle: batch <-> XCD
  const int q = ((blk >> 3) << 2) + (threadIdx.x >> 6);
  const int s = lane >> 5;                    // sample parity
  const int hl = (lane >> 3) & 3;             // head within group
  const int d = lane & 7;                     // dim octet
  const int h = hg * 4 + hl;
  const int col = hg * 256 + hl * 64 + d * 8;

  const float* Qp = Q + ((size_t)b * LSEQ + q) * D_MODEL + col;
  const float4 q0 = *(const float4*)Qp;
  const float4 q1 = *(const float4*)(Qp + 4);
  const float* Kb = K + (size_t)b * LSEQ * D_MODEL + col;
  const int* sp = sidx + (size_t)q * S;

  auto rowp = [&](int j) -> const float* {
    int jj = j + s;
    int row = sp[(jj < S) ? jj : (S - 1)];
    return Kb + (size_t)row * D_MODEL;
  };

  const float* pr0 = rowp(0);
  float4 a0 = *(const float4*)pr0, b0 = *(const float4*)(pr0 + 4);
  const float* pr1 = rowp(2);
  float4 a1 = *(const float4*)pr1, b1 = *(const float4*)(pr1 + 4);

  float mx = -3.4e38f, sum = 0.0f;
  for (int j = 0; j < S; j += 2) {
    const float4 ca = a0, cb = b0;
    a0 = a1; b0 = b1;
    const float* pn = rowp(j + 4);
    a1 = *(const float4*)pn;
    b1 = *(const float4*)(pn + 4);
    float p = ca.x * q0.x + ca.y * q0.y + ca.z * q0.z + ca.w * q0.w +
              cb.x * q1.x + cb.y * q1.y + cb.z * q1.z + cb.w * q1.w;
    p += __shfl_xor(p, 1, 64);
    p += __shfl_xor(p, 2, 64);
    p += __shfl_xor(p, 4, 64);   // 8-lane group done
    if (j + s < S) {
      mx = fmaxf(mx, p);
      sum += p;
    }
  }
  mx = fmaxf(mx, __shfl_xor(mx, 32, 64));
  sum += __shfl_xor(sum, 32, 64);
  if (s == 0 && d == 0)
    M[((size_t)(b * NHEADS + h)) * LSEQ + q] = mx - sum / (float)S;
}

// ===================== top-U indices per (b,h) =============================
// wave-shuffle argmax (6 stages) + 2 barriers/iter.
__global__ __launch_bounds__(256) void topk_kernel(
    const float* __restrict__ M, int* __restrict__ Mtop, int U) {
  __shared__ float vals[LSEQ];
  __shared__ float wbest[4];
  __shared__ int widx[4];
  int bh = blockIdx.x;
  int t = threadIdx.x;
  const int w = t >> 6, lane = t & 63;
  for (int i = t; i < LSEQ; i += 256) vals[i] = M[(size_t)bh * LSEQ + i];
  __syncthreads();
  for (int it = 0; it < U; ++it) {
    float best = -3.4e38f; int bi = 0x7fffffff;
    for (int i = t; i < LSEQ; i += 256) {
      float v = vals[i];
      if (v > best) { best = v; bi = i; }
    }
#pragma unroll
    for (int o = 1; o < 64; o <<= 1) {
      float ov = __shfl_xor(best, o, 64);
      int oi = __shfl_xor(bi, o, 64);
      if (ov > best || (ov == best && oi < bi)) { best = ov; bi = oi; }
    }
    if (lane == 0) { wbest[w] = best; widx[w] = bi; }
    __syncthreads();
    if (t == 0) {
      float B = wbest[0]; int I = widx[0];
#pragma unroll
      for (int w2 = 1; w2 < 4; ++w2)
        if (wbest[w2] > B || (wbest[w2] == B && widx[w2] < I)) {
          B = wbest[w2]; I = widx[w2];
        }
      Mtop[(size_t)bh * U + it] = I;
      vals[I] = -3.4e38f;
    }
    __syncthreads();
  }
}

// ============== flash attention over top-U rows, key-split =================
// MFMA QK^T (swapped: S^T = mfma(K, Q)) + fp32 VALU PV.
__global__ __launch_bounds__(256, 2) void attn_flash(
    const float* __restrict__ Q, const float* __restrict__ K,
    const float* __restrict__ V, const int* __restrict__ Mtop,
    float* __restrict__ part_ctx, float* __restrict__ part_m,
    float* __restrict__ part_l, int U, int nsplit, int chunks_per_block) {
  __shared__ u16 KhS[64 * 72];
  __shared__ u16 KlS[64 * 72];
  __shared__ float VsS[64 * 68];
  const int bh = blockIdx.y, split = blockIdx.x;
  const int h = bh & (NHEADS - 1), b = bh >> 3;
  const int t = threadIdx.x, w = t >> 6, lane = t & 63;
  const int fr = lane & 15, quad = lane >> 4;

  const int qi = w * 16 + fr;
  const int qrow = (qi < U) ? Mtop[(size_t)bh * U + qi] : Mtop[(size_t)bh * U];
  const float4* Qr = (const float4*)(Q + ((size_t)(b * LSEQ) + qrow) * D_MODEL + h * EDIM);
  float4 qa = Qr[quad * 2], qb = Qr[quad * 2 + 1];
  float4 qc = Qr[quad * 2 + 8], qd = Qr[quad * 2 + 9];
  short8 qh0, ql0, qh1, ql1;
  {
    u16 hh, ll;
    split2(qa.x, hh, ll); qh0[0] = (short)hh; ql0[0] = (short)ll;
    split2(qa.y, hh, ll); qh0[1] = (short)hh; ql0[1] = (short)ll;
    split2(qa.z, hh, ll); qh0[2] = (short)hh; ql0[2] = (short)ll;
    split2(qa.w, hh, ll); qh0[3] = (short)hh; ql0[3] = (short)ll;
    split2(qb.x, hh, ll); qh0[4] = (short)hh; ql0[4] = (short)ll;
    split2(qb.y, hh, ll); qh0[5] = (short)hh; ql0[5] = (short)ll;
    split2(qb.z, hh, ll); qh0[6] = (short)hh; ql0[6] = (short)ll;
    split2(qb.w, hh, ll); qh0[7] = (short)hh; ql0[7] = (short)ll;
    split2(qc.x, hh, ll); qh1[0] = (short)hh; ql1[0] = (short)ll;
    split2(qc.y, hh, ll); qh1[1] = (short)hh; ql1[1] = (short)ll;
    split2(qc.z, hh, ll); qh1[2] = (short)hh; ql1[2] = (short)ll;
    split2(qc.w, hh, ll); qh1[3] = (short)hh; ql1[3] = (short)ll;
    split2(qd.x, hh, ll); qh1[4] = (short)hh; ql1[4] = (short)ll;
    split2(qd.y, hh, ll); qh1[5] = (short)hh; ql1[5] = (short)ll;
    split2(qd.z, hh, ll); qh1[6] = (short)hh; ql1[6] = (short)ll;
    split2(qd.w, hh, ll); qh1[7] = (short)hh; ql1[7] = (short)ll;
  }

  float4 c4[16];
#pragma unroll
  for (int i = 0; i < 16; ++i) c4[i] = make_float4(0.f, 0.f, 0.f, 0.f);
  float m = -1e30f, l = 0.0f;

  const int r = t >> 2, cg = t & 3;

  const int k_base = split * (chunks_per_block * 64);
  for (int c = 0; c < chunks_per_block; ++c) {
    const int k0 = k_base + c * 64;
    const float4* Kg4 = (const float4*)(K + ((size_t)(b * LSEQ) + k0 + r) * D_MODEL + h * EDIM);
    const float4* Vg4 = (const float4*)(V + ((size_t)(b * LSEQ) + k0 + r) * D_MODEL + h * EDIM);
#pragma unroll
    for (int i = 0; i < 4; ++i) {
      const int f4 = cg + 4 * i;
      float4 kv = Kg4[f4];
      float4 vv = Vg4[f4];
      ushort4 hh, ll;
      split2(kv.x, hh.x, ll.x);
      split2(kv.y, hh.y, ll.y);
      split2(kv.z, hh.z, ll.z);
      split2(kv.w, hh.w, ll.w);
      *(ushort4*)&KhS[r * 72 + f4 * 4] = hh;
      *(ushort4*)&KlS[r * 72 + f4 * 4] = ll;
      *(float4*)&VsS[r * 68 + f4 * 4] = vv;
    }
    __syncthreads();

    f32x4 acc[4];
#pragma unroll
    for (int mt = 0; mt < 4; ++mt) acc[mt] = (f32x4){0.f, 0.f, 0.f, 0.f};
#pragma unroll
    for (int mt = 0; mt < 4; ++mt) {
      short8 kh = *(const short8*)&KhS[(mt * 16 + fr) * 72 + quad * 8];
      short8 kl = *(const short8*)&KlS[(mt * 16 + fr) * 72 + quad * 8];
      acc[mt] = __builtin_amdgcn_mfma_f32_16x16x32_bf16(kh, qh0, acc[mt], 0, 0, 0);
      acc[mt] = __builtin_amdgcn_mfma_f32_16x16x32_bf16(kh, ql0, acc[mt], 0, 0, 0);
      acc[mt] = __builtin_amdgcn_mfma_f32_16x16x32_bf16(kl, qh0, acc[mt], 0, 0, 0);
    }
#pragma unroll
    for (int mt = 0; mt < 4; ++mt) {
      short8 kh = *(const short8*)&KhS[(mt * 16 + fr) * 72 + 32 + quad * 8];
      short8 kl = *(const short8*)&KlS[(mt * 16 + fr) * 72 + 32 + quad * 8];
      acc[mt] = __builtin_amdgcn_mfma_f32_16x16x32_bf16(kh, qh1, acc[mt], 0, 0, 0);
      acc[mt] = __builtin_amdgcn_mfma_f32_16x16x32_bf16(kh, ql1, acc[mt], 0, 0, 0);
      acc[mt] = __builtin_amdgcn_mfma_f32_16x16x32_bf16(kl, qh1, acc[mt], 0, 0, 0);
    }

    float cm = -3.4e38f;
#pragma unroll
    for (int mt = 0; mt < 4; ++mt) {
#pragma unroll
      for (int rr = 0; rr < 4; ++rr) {
        float s = acc[mt][rr] * 0.125f;
        acc[mt][rr] = s;
        cm = fmaxf(cm, s);
      }
    }
    cm = fmaxf(cm, __shfl_xor(cm, 16, 64));
    cm = fmaxf(cm, __shfl_xor(cm, 32, 64));
    float mn = fmaxf(m, cm);
    if (mn > m) {
      float f = __expf(m - mn);
      l *= f;
#pragma unroll
      for (int i = 0; i < 16; ++i) {
        c4[i].x *= f; c4[i].y *= f; c4[i].z *= f; c4[i].w *= f;
      }
      m = mn;
    }
    float psum = 0.0f;
#pragma unroll
    for (int mt = 0; mt < 4; ++mt) {
#pragma unroll
      for (int rr = 0; rr < 4; ++rr) {
        float p = __expf(acc[mt][rr] - m);
        acc[mt][rr] = p;
        psum += p;
      }
    }
    l += psum;

#pragma unroll
    for (int mt = 0; mt < 4; ++mt) {
#pragma unroll
      for (int rr = 0; rr < 4; ++rr) {
        const int krow = mt * 16 + quad * 4 + rr;
        const float4* vr = (const float4*)&VsS[krow * 68];
        const float p = acc[mt][rr];
#pragma unroll
        for (int i = 0; i < 16; ++i) {
          float4 vv = vr[i];
          c4[i].x += p * vv.x; c4[i].y += p * vv.y;
          c4[i].z += p * vv.z; c4[i].w += p * vv.w;
        }
      }
    }
    __syncthreads();
  }

#pragma unroll
  for (int i = 0; i < 16; ++i) {
    c4[i].x += __shfl_xor(c4[i].x, 16, 64);
    c4[i].y += __shfl_xor(c4[i].y, 16, 64);
    c4[i].z += __shfl_xor(c4[i].z, 16, 64);
    c4[i].w += __shfl_xor(c4[i].w, 16, 64);
    c4[i].x += __shfl_xor(c4[i].x, 32, 64);
    c4[i].y += __shfl_xor(c4[i].y, 32, 64);
    c4[i].z += __shfl_xor(c4[i].z, 32, 64);
    c4[i].w += __shfl_xor(c4[i].w, 32, 64);
  }
  l += __shfl_xor(l, 16, 64);
  l += __shfl_xor(l, 32, 64);

  if (quad == 0 && qi < U) {
    part_m[(size_t)(bh * nsplit + split) * 64 + qi] = m;
    part_l[(size_t)(bh * nsplit + split) * 64 + qi] = l;
  }
  float* pc = part_ctx + (size_t)(bh * nsplit + split) * 4096;
  if (quad == 0) {
#pragma unroll
    for (int ii = 0; ii < 16; ++ii) pc[ii * 64 + qi] = (&c4[ii >> 2].x)[ii & 3];
  } else if (quad == 1) {
#pragma unroll
    for (int ii = 0; ii < 16; ++ii) pc[(16 + ii) * 64 + qi] = (&c4[4 + (ii >> 2)].x)[ii & 3];
  } else if (quad == 2) {
#pragma unroll
    for (int ii = 0; ii < 16; ++ii) pc[(32 + ii) * 64 + qi] = (&c4[8 + (ii >> 2)].x)[ii & 3];
  } else {
#pragma unroll
    for (int ii = 0; ii < 16; ++ii) pc[(48 + ii) * 64 + qi] = (&c4[12 + (ii >> 2)].x)[ii & 3];
  }
}

// =================== combine key-split flash partials ======================
__global__ __launch_bounds__(256) void attn_combine(
    const float* __restrict__ part_ctx, const float* __restrict__ part_m,
    const float* __restrict__ part_l, float* __restrict__ ctxTop,
    int U, int nsplit) {
  __shared__ float F[16][64];
  const int bh = blockIdx.x;
  const int t = threadIdx.x, lane = t & 63, grp = t >> 6;
  if (grp == 0) {
    float M = -3.4e38f;
    for (int s = 0; s < nsplit; ++s)
      M = fmaxf(M, part_m[(size_t)(bh * nsplit + s) * 64 + lane]);
    float L = 0.0f;
    for (int s = 0; s < nsplit; ++s)
      L += part_l[(size_t)(bh * nsplit + s) * 64 + lane] *
           __expf(part_m[(size_t)(bh * nsplit + s) * 64 + lane] - M);
    float invL = 1.0f / L;
    for (int s = 0; s < nsplit; ++s)
      F[s][lane] = __expf(part_m[(size_t)(bh * nsplit + s) * 64 + lane] - M) * invL;
  }
  __syncthreads();
  for (int ei = 0; ei < 16; ++ei) {
    int e = grp * 16 + ei;
    float acc = 0.0f;
    for (int s = 0; s < nsplit; ++s)
      acc += F[s][lane] * part_ctx[(size_t)(bh * nsplit + s) * 4096 + e * 64 + lane];
    if (lane < U) ctxTop[((size_t)bh * U + lane) * 64 + e] = acc;
  }
}

// ====================== V.mean over keys per (b,h), split 8x ===============
__global__ __launch_bounds__(256) void vmean_part(
    const float* __restrict__ V, float* __restrict__ Vm) {
  __shared__ float part[4][EDIM];
  const int bh = blockIdx.x, chunk = blockIdx.y;
  const int h = bh & (NHEADS - 1), b = bh >> 3;
  const int t = threadIdx.x;
  const int e = t & 63, c = t >> 6;
  float s = 0.0f;
  const int k0 = chunk * 512 + c * 128;
  for (int k = k0; k < k0 + 128; ++k)
    s += V[((size_t)b * LSEQ + k) * D_MODEL + h * EDIM + e];
  part[c][e] = s;
  __syncthreads();
  if (c == 0)
    atomicAdd(&Vm[(size_t)bh * EDIM + e],
              (part[0][e] + part[1][e] + part[2][e] + part[3][e]) *
                  (1.0f / (float)LSEQ));
}

// ============ base_out[b] = concat_h(Vmean[b,h]) @ W_out + b_out ===========
__global__ __launch_bounds__(256) void base_out_kernel(
    const float* __restrict__ Vm, const float* __restrict__ Wout,
    const float* __restrict__ bout, float* __restrict__ base) {
  __shared__ float cb[D_MODEL];
  int b = blockIdx.x;
  int t = threadIdx.x;
  for (int d = t; d < D_MODEL; d += 256) cb[d] = Vm[(size_t)b * D_MODEL + d];
  __syncthreads();
  for (int n = t; n < D_MODEL; n += 256) {
    float s = bout[n];
    for (int d = 0; d < D_MODEL; ++d) s += cb[d] * Wout[(size_t)d * D_MODEL + n];
    base[(size_t)b * D_MODEL + n] = s;
  }
}

// ================== broadcast base row into all output rows ================
__global__ __launch_bounds__(256) void fill_out(
    const float* __restrict__ base, float* __restrict__ out) {
  size_t i = (size_t)blockIdx.x * 256 + threadIdx.x;
  int n4 = (int)(i & 127);
  size_t bq = i >> 7;
  int b = (int)(bq >> 12);
  float4 v = ((const float4*)base)[(size_t)b * 128 + n4];
  ((float4*)out)[i] = v;
}

// ====== add (ctxTop - Vmean) @ W_out[h-slice] into the top rows (MFMA) =====
__global__ __launch_bounds__(256, 1) void delta_out_mfma(
    const float* __restrict__ ctxTop, const float* __restrict__ Vm,
    const int* __restrict__ Mtop, const u16* __restrict__ WoutTP,
    float* __restrict__ out, int U) {
  __shared__ u16 Dh[64 * 72];
  __shared__ u16 Dl[64 * 72];
  __shared__ int qr[64];
  const int bh = blockIdx.x;
  const int h = bh & (NHEADS - 1), b = bh >> 3;
  const int t = threadIdx.x, lane = t & 63, wv = t >> 6;
  const int fr = lane & 15, quad = lane >> 4;

  {
    const int r = t >> 2, c0 = (t & 3) * 16;
#pragma unroll
    for (int j = 0; j < 4; ++j) {
      float4 v = make_float4(0.f, 0.f, 0.f, 0.f);
      if (r < U) {
        float4 cv = *(const float4*)(ctxTop + ((size_t)bh * U + r) * EDIM + c0 + j * 4);
        float4 mv = *(const float4*)(Vm + (size_t)bh * EDIM + c0 + j * 4);
        v = make_float4(cv.x - mv.x, cv.y - mv.y, cv.z - mv.z, cv.w - mv.w);
      }
      ushort4 hh, ll;
      split2(v.x, hh.x, ll.x);
      split2(v.y, hh.y, ll.y);
      split2(v.z, hh.z, ll.z);
      split2(v.w, hh.w, ll.w);
      *(ushort4*)&Dh[r * 72 + c0 + j * 4] = hh;
      *(ushort4*)&Dl[r * 72 + c0 + j * 4] = ll;
    }
  }
  if (t < 64) qr[t] = (t < U) ? Mtop[(size_t)bh * U + t] : -1;
  __syncthreads();

  f32x4 acc[32];   // [mt(4)][nt(8)]
#pragma unroll
  for (int i = 0; i < 32; ++i) acc[i] = (f32x4){0.f, 0.f, 0.f, 0.f};

  const u16* Wh = WoutTP;
  const u16* Wl = WoutTP + 262144;
  const int bq = (quad ^ (fr & 3)) * 8;   // matches cvt_w pre-swizzle

#pragma unroll
  for (int ks = 0; ks < 2; ++ks) {
    short8 a_h[4], a_l[4];
#pragma unroll
    for (int mt = 0; mt < 4; ++mt) {
      a_h[mt] = *(const short8*)&Dh[(mt * 16 + fr) * 72 + ks * 32 + quad * 8];
      a_l[mt] = *(const short8*)&Dl[(mt * 16 + fr) * 72 + ks * 32 + quad * 8];
    }
#pragma unroll
    for (int nt = 0; nt < 8; ++nt) {
      const int n = wv * 128 + nt * 16 + fr;
      const size_t off = (size_t)n * 512 + h * EDIM + ks * 32 + bq;
      short8 b_h = *(const short8*)&Wh[off];
      short8 b_l = *(const short8*)&Wl[off];
#pragma unroll
      for (int mt = 0; mt < 4; ++mt) {
        acc[mt * 8 + nt] = __builtin_amdgcn_mfma_f32_16x16x32_bf16(
            a_h[mt], b_h, acc[mt * 8 + nt], 0, 0, 0);
        acc[mt * 8 + nt] = __builtin_amdgcn_mfma_f32_16x16x32_bf16(
            a_h[mt], b_l, acc[mt * 8 + nt], 0, 0, 0);
        acc[mt * 8 + nt] = __builtin_amdgcn_mfma_f32_16x16x32_bf16(
            a_l[mt], b_h, acc[mt * 8 + nt], 0, 0, 0);
      }
    }
  }

  int qreg[16];
#pragma unroll
  for (int mt = 0; mt < 4; ++mt)
#pragma unroll
    for (int r4 = 0; r4 < 4; ++r4) qreg[mt * 4 + r4] = qr[mt * 16 + quad * 4 + r4];
#pragma unroll
  for (int mt = 0; mt < 4; ++mt)
#pragma unroll
    for (int nt = 0; nt < 8; ++nt) {
      const f32x4 a = acc[mt * 8 + nt];
      const int n = wv * 128 + nt * 16 + fr;
#pragma unroll
      for (int r4 = 0; r4 < 4; ++r4) {
        const int q = qreg[mt * 4 + r4];
        if (q >= 0)
          atomicAdd(out + ((size_t)b * LSEQ + q) * D_MODEL + n, a[r4]);
      }
    }
}

// ===========================================================================
extern "C" void kernel_launch(void* const* d_in, const int* in_sizes, int n_in,
                              void* d_out, int out_size, void* d_ws, size_t ws_size,
                              hipStream_t stream) {
  const float* query  = (const float*)d_in[0];
  const float* key_in = (const float*)d_in[1];
  const float* value  = (const float*)d_in[2];
  const float* W_Q    = (const float*)d_in[3];
  const float* W_K    = (const float*)d_in[4];
  const float* W_V    = (const float*)d_in[5];
  const float* W_out  = (const float*)d_in[6];
  const float* b_out  = (const float*)d_in[7];
  const int*   sidx   = (const int*)d_in[8];
  float* out = (float*)d_out;

  const int S = in_sizes[8] / LSEQ;   // 41
  const int U = S;

  char* ws = (char*)d_ws;
  size_t o = 0;
  float* Qf     = (float*)(ws + o); o += (size_t)BATCH * LSEQ * D_MODEL * 4;
  float* Kf     = (float*)(ws + o); o += (size_t)BATCH * LSEQ * D_MODEL * 4;
  float* Vf     = (float*)(ws + o); o += (size_t)BATCH * LSEQ * D_MODEL * 4;
  int*   Mtop   = (int*)  (ws + o); o += ((size_t)64 * U * 4 + 255) & ~255ULL;
  float* ctxTop = (float*)(ws + o); o += ((size_t)64 * U * EDIM * 4 + 255) & ~255ULL;
  float* Vm     = (float*)(ws + o); o += 16384;
  float* baseO  = (float*)(ws + o); o += 16384;
  u16*   Wpl    = (u16*)  (ws + o); o += (size_t)4 * 524288 * 2;   // 4 MB
  size_t unionOff = o;   // M / flash partials (disjoint lifetimes)

  float* M = (float*)(ws + unionOff);            // 1 MB
  int nsplit = 16;
  for (;;) {
    size_t need = unionOff + 2 * ((size_t)64 * nsplit * 64 * 4)
                  + (size_t)64 * nsplit * 4096 * 4;
    if (need <= ws_size || nsplit == 1) break;
    nsplit >>= 1;
  }
  float* part_m   = (float*)(ws + unionOff);
  float* part_l   = part_m + (size_t)64 * nsplit * 64;
  float* part_ctx = part_l + (size_t)64 * nsplit * 64;
  const int chunks_per_block = 64 / nsplit;

  // ---- projections via fused split-bf16 MFMA GEMM (single-buffer) ----
  cvt_w<<<dim3(8, 8, 4), 256, 0, stream>>>(W_Q, W_K, W_V, W_out, Wpl);
  gemm_fused<<<dim3(4, 256, 3), 256, 0, stream>>>(
      query, key_in, value, Wpl, Qf, Kf, Vf);

  qk_sample_half<<<(BATCH * LSEQ) / 4, 256, 0, stream>>>(Qf, Kf, sidx, M, S, 0);
  qk_sample_half<<<(BATCH * LSEQ) / 4, 256, 0, stream>>>(Qf, Kf, sidx, M, S, 1);
  topk_kernel<<<BATCH * NHEADS, 256, 0, stream>>>(M, Mtop, U);
  attn_flash<<<dim3(nsplit, BATCH * NHEADS), 256, 0, stream>>>(
      Qf, Kf, Vf, Mtop, part_ctx, part_m, part_l, U, nsplit, chunks_per_block);
  attn_combine<<<BATCH * NHEADS, 256, 0, stream>>>(
      part_ctx, part_m, part_l, ctxTop, U, nsplit);
  hipMemsetAsync(Vm, 0, (size_t)BATCH * NHEADS * EDIM * 4, stream);
  vmean_part<<<dim3(BATCH * NHEADS, 8), 256, 0, stream>>>(Vf, Vm);
  base_out_kernel<<<BATCH, 256, 0, stream>>>(Vm, W_out, b_out, baseO);
  fill_out<<<(BATCH * LSEQ * (D_MODEL / 4)) / 256, 256, 0, stream>>>(baseO, out);
  delta_out_mfma<<<BATCH * NHEADS, 256, 0, stream>>>(
      ctxTop, Vm, Mtop, Wpl + (size_t)3 * 524288, out, U);
}